// Round 1
// baseline (159.596 us; speedup 1.0000x reference)
//
#include <hip/hip_runtime.h>
#include <hip/hip_bf16.h>

// out[e] = sum_d |nodes[r[e]][d] - nodes[c[e]][d]| * w[d] + b[0]
// E = 600000, D = 128, N_OUT = 1, fp32 throughout.
//
// Strategy: 32 lanes per edge (2 edges per wave64). Each lane loads one
// float4 from row r and row c (32 lanes x 16B = 512B = full row, coalesced),
// computes |a-b| dot w partial for 4 elems, then 5-step __shfl_xor reduction
// within the 32-lane half. The 51.2 MB node table lives in L3/L2, so the
// 614 MB of gathers are cache-bandwidth-bound, not HBM-bound.

#define D_FEAT 128

__global__ __launch_bounds__(256) void mlp_decoder_edge_kernel(
    const float* __restrict__ nodes,
    const int*   __restrict__ r_idx,
    const int*   __restrict__ c_idx,
    const float* __restrict__ w,
    const float* __restrict__ b,
    float*       __restrict__ out,
    int n_edges)
{
    const int tid  = blockIdx.x * blockDim.x + threadIdx.x;
    const int lane = tid & 31;        // lane within the 32-thread edge group
    const int edge = tid >> 5;        // one edge per 32 threads
    if (edge >= n_edges) return;

    const int r = r_idx[edge];
    const int c = c_idx[edge];

    // w fits in L1; every lane reads its own float4 slice (broadcast across edges)
    const float4 wv = ((const float4*)w)[lane];

    const float4 av = ((const float4*)(nodes + (size_t)r * D_FEAT))[lane];
    const float4 bv = ((const float4*)(nodes + (size_t)c * D_FEAT))[lane];

    float s = fabsf(av.x - bv.x) * wv.x
            + fabsf(av.y - bv.y) * wv.y
            + fabsf(av.z - bv.z) * wv.z
            + fabsf(av.w - bv.w) * wv.w;

    // Reduce across the 32-lane group. XOR masks 16..1 never cross the
    // 32-lane boundary, so the two edges in a wave64 stay independent.
    #pragma unroll
    for (int off = 16; off > 0; off >>= 1)
        s += __shfl_xor(s, off, 64);

    if (lane == 0)
        out[edge] = s + b[0];
}

extern "C" void kernel_launch(void* const* d_in, const int* in_sizes, int n_in,
                              void* d_out, int out_size, void* d_ws, size_t ws_size,
                              hipStream_t stream) {
    const float* nodes = (const float*)d_in[0];   // [N_NODES, 128] f32
    const int*   r_idx = (const int*)d_in[1];     // [E] int
    const int*   c_idx = (const int*)d_in[2];     // [E] int
    const float* w     = (const float*)d_in[3];   // [128, 1] f32
    const float* b     = (const float*)d_in[4];   // [1] f32
    float*       out   = (float*)d_out;           // [E] f32

    const int n_edges = in_sizes[1];
    // 32 threads per edge, 256-thread blocks -> 8 edges/block
    const int threads_needed = n_edges * 32;
    const int block = 256;
    const int grid  = (threads_needed + block - 1) / block;

    mlp_decoder_edge_kernel<<<grid, block, 0, stream>>>(
        nodes, r_idx, c_idx, w, b, out, n_edges);
}

// Round 2
// 131.070 us; speedup vs baseline: 1.2176x; 1.2176x over previous
//
#include <hip/hip_runtime.h>
#include <hip/hip_bf16.h>
#include <hip/hip_fp16.h>

// out[e] = sum_d |nodes[r[e]][d] - nodes[c[e]][d]| * w[d] + b[0]
// E = 600000, D = 128, N_OUT = 1.
//
// R1 measured: FETCH_SIZE 287 MB @ 3.45 TB/s = the whole 85 us. Random
// gathers of 512B fp32 rows miss per-XCD L2 (4 MB vs 51.2 MB table).
// R2: convert table to fp16 (25.6 MB) once per call into d_ws, halving
// gather bytes. Accuracy budget: threshold 4.8e-2, fp16 adds ~1e-3.

#define D_FEAT 128

// ---- pass 1: fp32 -> fp16 table conversion (streaming) ----
// each thread converts 8 floats -> 8 halves (2x float4 load, 1x float4 store)
__global__ __launch_bounds__(256) void convert_f32_to_f16(
    const float* __restrict__ src, __half* __restrict__ dst, int n8)
{
    const int i = blockIdx.x * blockDim.x + threadIdx.x;
    if (i >= n8) return;
    const float4* s = (const float4*)src + 2 * (size_t)i;
    const float4 a = s[0];
    const float4 c = s[1];
    float4 packed;
    ((__half2*)&packed)[0] = __floats2half2_rn(a.x, a.y);
    ((__half2*)&packed)[1] = __floats2half2_rn(a.z, a.w);
    ((__half2*)&packed)[2] = __floats2half2_rn(c.x, c.y);
    ((__half2*)&packed)[3] = __floats2half2_rn(c.z, c.w);
    ((float4*)dst)[i] = packed;  // 16 B = 8 halves
}

// ---- pass 2: edge gather from fp16 table ----
// 16 lanes per edge (4 edges per wave64). Each lane loads 16B = 8 halves
// of row r and row c (16 lanes x 16B = full 256B row, coalesced), computes
// 8 |a-b|*w terms in fp32, then 4-step shfl_xor reduction within 16 lanes.
__global__ __launch_bounds__(256) void gather_edges_f16(
    const __half* __restrict__ tbl,
    const int*   __restrict__ r_idx,
    const int*   __restrict__ c_idx,
    const float* __restrict__ w,
    const float* __restrict__ b,
    float*       __restrict__ out,
    int n_edges)
{
    const int tid  = blockIdx.x * blockDim.x + threadIdx.x;
    const int lane = tid & 15;
    const int edge = tid >> 4;
    if (edge >= n_edges) return;

    const int r = r_idx[edge];
    const int c = c_idx[edge];

    // w is 512B total, L1-resident broadcast; lane covers w[8*lane .. +8)
    const float4 w0 = ((const float4*)w)[2 * lane + 0];
    const float4 w1 = ((const float4*)w)[2 * lane + 1];

    const float4 araw = ((const float4*)(tbl + (size_t)r * D_FEAT))[lane];
    const float4 braw = ((const float4*)(tbl + (size_t)c * D_FEAT))[lane];
    const __half2* ah = (const __half2*)&araw;
    const __half2* bh = (const __half2*)&braw;

    const float2 a0 = __half22float2(ah[0]), b0 = __half22float2(bh[0]);
    const float2 a1 = __half22float2(ah[1]), b1 = __half22float2(bh[1]);
    const float2 a2 = __half22float2(ah[2]), b2 = __half22float2(bh[2]);
    const float2 a3 = __half22float2(ah[3]), b3 = __half22float2(bh[3]);

    float s = fabsf(a0.x - b0.x) * w0.x
            + fabsf(a0.y - b0.y) * w0.y
            + fabsf(a1.x - b1.x) * w0.z
            + fabsf(a1.y - b1.y) * w0.w
            + fabsf(a2.x - b2.x) * w1.x
            + fabsf(a2.y - b2.y) * w1.y
            + fabsf(a3.x - b3.x) * w1.z
            + fabsf(a3.y - b3.y) * w1.w;

    // Reduce across the 16-lane group (xor masks < 16 never cross groups).
    #pragma unroll
    for (int off = 8; off > 0; off >>= 1)
        s += __shfl_xor(s, off, 64);

    if (lane == 0)
        out[edge] = s + b[0];
}

// ---- fallback (R1 kernel): direct fp32 gather, if ws too small ----
__global__ __launch_bounds__(256) void gather_edges_f32(
    const float* __restrict__ nodes,
    const int*   __restrict__ r_idx,
    const int*   __restrict__ c_idx,
    const float* __restrict__ w,
    const float* __restrict__ b,
    float*       __restrict__ out,
    int n_edges)
{
    const int tid  = blockIdx.x * blockDim.x + threadIdx.x;
    const int lane = tid & 31;
    const int edge = tid >> 5;
    if (edge >= n_edges) return;

    const int r = r_idx[edge];
    const int c = c_idx[edge];

    const float4 wv = ((const float4*)w)[lane];
    const float4 av = ((const float4*)(nodes + (size_t)r * D_FEAT))[lane];
    const float4 bv = ((const float4*)(nodes + (size_t)c * D_FEAT))[lane];

    float s = fabsf(av.x - bv.x) * wv.x
            + fabsf(av.y - bv.y) * wv.y
            + fabsf(av.z - bv.z) * wv.z
            + fabsf(av.w - bv.w) * wv.w;

    #pragma unroll
    for (int off = 16; off > 0; off >>= 1)
        s += __shfl_xor(s, off, 64);

    if (lane == 0)
        out[edge] = s + b[0];
}

extern "C" void kernel_launch(void* const* d_in, const int* in_sizes, int n_in,
                              void* d_out, int out_size, void* d_ws, size_t ws_size,
                              hipStream_t stream) {
    const float* nodes = (const float*)d_in[0];   // [N_NODES, 128] f32
    const int*   r_idx = (const int*)d_in[1];     // [E] int
    const int*   c_idx = (const int*)d_in[2];     // [E] int
    const float* w     = (const float*)d_in[3];   // [128, 1] f32
    const float* b     = (const float*)d_in[4];   // [1] f32
    float*       out   = (float*)d_out;           // [E] f32

    const int n_edges   = in_sizes[1];
    const int n_nodes_f = in_sizes[0];            // n_nodes * 128 floats
    const size_t tbl_bytes = (size_t)n_nodes_f * sizeof(__half);

    if (ws_size >= tbl_bytes && (n_nodes_f & 7) == 0) {
        __half* tbl = (__half*)d_ws;

        // pass 1: convert table to fp16
        const int n8 = n_nodes_f / 8;
        const int cblock = 256;
        const int cgrid  = (n8 + cblock - 1) / cblock;
        convert_f32_to_f16<<<cgrid, cblock, 0, stream>>>(nodes, tbl, n8);

        // pass 2: gather; 16 threads/edge, 256-thread blocks -> 16 edges/block
        const int block = 256;
        const int grid  = (n_edges * 16 + block - 1) / block;
        gather_edges_f16<<<grid, block, 0, stream>>>(
            tbl, r_idx, c_idx, w, b, out, n_edges);
    } else {
        // fallback: direct fp32 gather (R1 path)
        const int block = 256;
        const int grid  = (n_edges * 32 + block - 1) / block;
        gather_edges_f32<<<grid, block, 0, stream>>>(
            nodes, r_idx, c_idx, w, b, out, n_edges);
    }
}

// Round 3
// 129.230 us; speedup vs baseline: 1.2350x; 1.0142x over previous
//
#include <hip/hip_runtime.h>
#include <hip/hip_bf16.h>
#include <hip/hip_fp16.h>

// out[e] = sum_d |nodes[r[e]][d] - nodes[c[e]][d]| * w[d] + b[0]
// E = 600000, D = 128, N_OUT = 1.
//
// R1: fp32 gather, FETCH 287 MB, 85 us (traffic-bound).
// R2: fp16 table in ws (convert pass ~13 us), FETCH 132 MB, gather 42.4 us
//     at only 3.1 TB/s miss traffic, VALUBusy 41% -> latency-limited, not BW.
// R3: raise memory-level parallelism: 8 lanes/edge, each lane loads 2x16B
//     per row -> 4 independent gather loads per thread (was 2), 8 edges/wave.

#define D_FEAT 128

// ---- pass 1: fp32 -> fp16 table conversion (streaming) ----
__global__ __launch_bounds__(256) void convert_f32_to_f16(
    const float* __restrict__ src, __half* __restrict__ dst, int n8)
{
    const int i = blockIdx.x * blockDim.x + threadIdx.x;
    if (i >= n8) return;
    const float4* s = (const float4*)src + 2 * (size_t)i;
    const float4 a = s[0];
    const float4 c = s[1];
    float4 packed;
    ((__half2*)&packed)[0] = __floats2half2_rn(a.x, a.y);
    ((__half2*)&packed)[1] = __floats2half2_rn(a.z, a.w);
    ((__half2*)&packed)[2] = __floats2half2_rn(c.x, c.y);
    ((__half2*)&packed)[3] = __floats2half2_rn(c.z, c.w);
    ((float4*)dst)[i] = packed;  // 16 B = 8 halves
}

// ---- pass 2: edge gather, 8 lanes/edge, 4 row-loads in flight/thread ----
// Row = 128 halves = 16 chunks of 16B. Lane l (0..7) loads chunks l and l+8,
// i.e. feature dims [8l,8l+8) and [64+8l,64+8l+8). Per load instruction the
// 64 lanes cover one full 128B line of each of 8 rows -> fully coalesced.
__global__ __launch_bounds__(256) void gather_edges_f16_ilp(
    const __half* __restrict__ tbl,
    const int*   __restrict__ r_idx,
    const int*   __restrict__ c_idx,
    const float* __restrict__ w,
    const float* __restrict__ b,
    float*       __restrict__ out,
    int n_edges)
{
    const int tid  = blockIdx.x * blockDim.x + threadIdx.x;
    const int lane = tid & 7;
    const int edge = tid >> 3;
    if (edge >= n_edges) return;

    const int r = r_idx[edge];
    const int c = c_idx[edge];

    const float4* arow = (const float4*)(tbl + (size_t)r * D_FEAT); // 16x 16B chunks
    const float4* brow = (const float4*)(tbl + (size_t)c * D_FEAT);

    // 4 independent gather loads issued back-to-back (the MLP we want):
    const float4 a0 = arow[lane];
    const float4 a1 = arow[lane + 8];
    const float4 b0 = brow[lane];
    const float4 b1 = brow[lane + 8];

    // w is 512 B, L1-resident broadcast. Chunk l -> w float4s {2l, 2l+1};
    // chunk l+8 -> {2l+16, 2l+17}.
    const float4 w00 = ((const float4*)w)[2 * lane + 0];
    const float4 w01 = ((const float4*)w)[2 * lane + 1];
    const float4 w10 = ((const float4*)w)[2 * lane + 16];
    const float4 w11 = ((const float4*)w)[2 * lane + 17];

    const __half2* a0h = (const __half2*)&a0;
    const __half2* b0h = (const __half2*)&b0;
    const __half2* a1h = (const __half2*)&a1;
    const __half2* b1h = (const __half2*)&b1;

    float s = 0.f;
    {
        const float2 x0 = __half22float2(a0h[0]), y0 = __half22float2(b0h[0]);
        const float2 x1 = __half22float2(a0h[1]), y1 = __half22float2(b0h[1]);
        const float2 x2 = __half22float2(a0h[2]), y2 = __half22float2(b0h[2]);
        const float2 x3 = __half22float2(a0h[3]), y3 = __half22float2(b0h[3]);
        s += fabsf(x0.x - y0.x) * w00.x + fabsf(x0.y - y0.y) * w00.y
           + fabsf(x1.x - y1.x) * w00.z + fabsf(x1.y - y1.y) * w00.w
           + fabsf(x2.x - y2.x) * w01.x + fabsf(x2.y - y2.y) * w01.y
           + fabsf(x3.x - y3.x) * w01.z + fabsf(x3.y - y3.y) * w01.w;
    }
    {
        const float2 x0 = __half22float2(a1h[0]), y0 = __half22float2(b1h[0]);
        const float2 x1 = __half22float2(a1h[1]), y1 = __half22float2(b1h[1]);
        const float2 x2 = __half22float2(a1h[2]), y2 = __half22float2(b1h[2]);
        const float2 x3 = __half22float2(a1h[3]), y3 = __half22float2(b1h[3]);
        s += fabsf(x0.x - y0.x) * w10.x + fabsf(x0.y - y0.y) * w10.y
           + fabsf(x1.x - y1.x) * w10.z + fabsf(x1.y - y1.y) * w10.w
           + fabsf(x2.x - y2.x) * w11.x + fabsf(x2.y - y2.y) * w11.y
           + fabsf(x3.x - y3.x) * w11.z + fabsf(x3.y - y3.y) * w11.w;
    }

    // Reduce across the 8-lane group (xor masks < 8 never cross groups).
    #pragma unroll
    for (int off = 4; off > 0; off >>= 1)
        s += __shfl_xor(s, off, 64);

    if (lane == 0)
        out[edge] = s + b[0];
}

// ---- fallback: direct fp32 gather (R1 path), if ws too small ----
__global__ __launch_bounds__(256) void gather_edges_f32(
    const float* __restrict__ nodes,
    const int*   __restrict__ r_idx,
    const int*   __restrict__ c_idx,
    const float* __restrict__ w,
    const float* __restrict__ b,
    float*       __restrict__ out,
    int n_edges)
{
    const int tid  = blockIdx.x * blockDim.x + threadIdx.x;
    const int lane = tid & 31;
    const int edge = tid >> 5;
    if (edge >= n_edges) return;

    const int r = r_idx[edge];
    const int c = c_idx[edge];

    const float4 wv = ((const float4*)w)[lane];
    const float4 av = ((const float4*)(nodes + (size_t)r * D_FEAT))[lane];
    const float4 bv = ((const float4*)(nodes + (size_t)c * D_FEAT))[lane];

    float s = fabsf(av.x - bv.x) * wv.x
            + fabsf(av.y - bv.y) * wv.y
            + fabsf(av.z - bv.z) * wv.z
            + fabsf(av.w - bv.w) * wv.w;

    #pragma unroll
    for (int off = 16; off > 0; off >>= 1)
        s += __shfl_xor(s, off, 64);

    if (lane == 0)
        out[edge] = s + b[0];
}

extern "C" void kernel_launch(void* const* d_in, const int* in_sizes, int n_in,
                              void* d_out, int out_size, void* d_ws, size_t ws_size,
                              hipStream_t stream) {
    const float* nodes = (const float*)d_in[0];   // [N_NODES, 128] f32
    const int*   r_idx = (const int*)d_in[1];     // [E] int
    const int*   c_idx = (const int*)d_in[2];     // [E] int
    const float* w     = (const float*)d_in[3];   // [128, 1] f32
    const float* b     = (const float*)d_in[4];   // [1] f32
    float*       out   = (float*)d_out;           // [E] f32

    const int n_edges   = in_sizes[1];
    const int n_nodes_f = in_sizes[0];            // n_nodes * 128 floats
    const size_t tbl_bytes = (size_t)n_nodes_f * sizeof(__half);

    if (ws_size >= tbl_bytes && (n_nodes_f & 7) == 0) {
        __half* tbl = (__half*)d_ws;

        const int n8 = n_nodes_f / 8;
        const int cblock = 256;
        const int cgrid  = (n8 + cblock - 1) / cblock;
        convert_f32_to_f16<<<cgrid, cblock, 0, stream>>>(nodes, tbl, n8);

        // 8 threads/edge, 256-thread blocks -> 32 edges/block
        const int block = 256;
        const int grid  = (n_edges * 8 + block - 1) / block;
        gather_edges_f16_ilp<<<grid, block, 0, stream>>>(
            tbl, r_idx, c_idx, w, b, out, n_edges);
    } else {
        const int block = 256;
        const int grid  = (n_edges * 32 + block - 1) / block;
        gather_edges_f32<<<grid, block, 0, stream>>>(
            nodes, r_idx, c_idx, w, b, out, n_edges);
    }
}